// Round 10
// baseline (127.940 us; speedup 1.0000x reference)
//
#include <hip/hip_runtime.h>
#include <math.h>

#define N_NODES 100000
#define D_INPUT 128
#define FDIM 128
#define A_HEADS 8
#define B_SEGS 512
#define D_OUTPUT 64
#define H_DIM 2304

typedef __attribute__((ext_vector_type(8))) __bf16 bf16x8;
typedef __attribute__((ext_vector_type(4))) float f32x4;

static __device__ inline unsigned short f2bfu(float f) {
    unsigned u = __builtin_bit_cast(unsigned, f);
    u += 0x7fffu + ((u >> 16) & 1u);
    return (unsigned short)(u >> 16);
}
static __device__ inline unsigned packbf(float a, float b) {
    return (unsigned)f2bfu(a) | ((unsigned)f2bfu(b) << 16);
}
static __device__ inline float bfl(unsigned u) {
    unsigned x = u << 16; return __builtin_bit_cast(float, x);
}
static __device__ inline float bfh(unsigned u) {
    unsigned x = u & 0xffff0000u; return __builtin_bit_cast(float, x);
}
static __device__ inline bf16x8 pack8(float4 a, float4 b) {
    union { unsigned u[4]; bf16x8 v; } r;
    r.u[0] = packbf(a.x, a.y); r.u[1] = packbf(a.z, a.w);
    r.u[2] = packbf(b.x, b.y); r.u[3] = packbf(b.z, b.w);
    return r.v;
}

// ---------------- segment boundaries (batch is sorted) ----------------
__global__ void seg_bounds_kernel(const int* __restrict__ batch, int n,
                                  int* __restrict__ seg_start) {
    int b = threadIdx.x;
    if (b > B_SEGS) return;
    int lo = 0, hi = n;
    while (lo < hi) {
        int mid = (lo + hi) >> 1;
        if (batch[mid] < b) lo = mid + 1; else hi = mid;
    }
    seg_start[b] = lo;
}

// ------- one-time weight conversion fp32 -> bf16 (packed u32), global -------
__global__ __launch_bounds__(256) void wconv_kernel(
        const float* __restrict__ W_in, const float* __restrict__ W_a,
        const float* __restrict__ W_out, unsigned* __restrict__ Wb,
        unsigned* __restrict__ Wa, unsigned* __restrict__ Wo,
        unsigned* __restrict__ Wagg) {
    int i = blockIdx.x * 256 + threadIdx.x;
    if (i < 8192) {
        float2 v = *(const float2*)(W_in + (size_t)i * 2);
        Wb[i] = packbf(v.x, v.y);
    } else if (i < 9216) {
        int j = i - 8192;
        if (j < 512) {
            float2 v = *(const float2*)(W_a + (size_t)j * 2);
            Wa[j] = packbf(v.x, v.y);
        } else Wa[j] = 0u;
    } else if (i < 17408) {
        int j = i - 9216;
        int row = j >> 7, cu = j & 127;
        float2 v = *(const float2*)(W_out + (size_t)row * H_DIM + cu * 2);
        Wo[j] = packbf(v.x, v.y);
    } else if (i < 82944) {
        int j = i - 17408;
        int row = j >> 10, cu = j & 1023;
        float2 v = *(const float2*)(W_out + (size_t)row * H_DIM + 256 + cu * 2);
        Wagg[j] = packbf(v.x, v.y);
    }
}

// ---- segment-major mega: one block per segment, 512 threads, fully fused ----
// All weights read as bf16 fragments straight from global (68KB total, L2-hot,
// shared by all blocks). LDS holds only the per-chunk XP tile + score + proj
// (39KB) -> 2 blocks/CU co-resident; cross-block TLP hides x-load and weight
// latency. NOTE: min-waves floor of 4 forces VGPR=64 -> accumulator spill
// (R6/R7: +200MB symmetric FETCH/WRITE). Keep the floor at 2.
__global__ __launch_bounds__(512, 2) void mega_kernel(
        const float* __restrict__ x, const int* __restrict__ seg_start,
        const float* __restrict__ b_in, const float* __restrict__ b_a,
        const float* __restrict__ b_out, const unsigned* __restrict__ Wb,
        const unsigned* __restrict__ Wa, const unsigned* __restrict__ Wo,
        const unsigned* __restrict__ Wagg, unsigned* __restrict__ out_part_u32,
        float* __restrict__ out) {
    __shared__ __align__(16) unsigned XP[128 * 68];    // xp chunk bf16 / agg f32
    __shared__ float scoref[128 * 8];
    __shared__ float projL[64];
    unsigned short* XPs = (unsigned short*)XP;
    float* XPf = (float*)XP;
    unsigned short* opart16 = (unsigned short*)out_part_u32;

    const int b = blockIdx.x;
    const int s0 = seg_start[b], s1 = seg_start[b + 1];
    const int cnt = s1 - s0;
    if (cnt == 0) return;
    const int t = threadIdx.x;

    const int w = t >> 6, l = t & 63, lr = l & 15, lk = l >> 4;
    const int a0 = w, f2 = l;     // agg ownership: head w, feature pair 2l,2l+1

    float binv[8];
#pragma unroll
    for (int nr = 0; nr < 8; ++nr) binv[nr] = b_in[nr * 16 + lr];
    const float ba = b_a[lr & 7];

    const f32x4 z4 = {0.f, 0.f, 0.f, 0.f};
    float sum0 = 0.f, sum1 = 0.f, mx0 = -INFINITY, mx1 = -INFINITY;

    for (int c0 = s0; c0 < s1; c0 += 128) {
        const int rc = min(128, s1 - c0);
        const int arowc = min(c0 + w * 16 + lr, s1 - 1);

        bf16x8 af[4];
#pragma unroll
        for (int ks = 0; ks < 4; ++ks) {
            const float4* xp4 = (const float4*)(x + (size_t)arowc * 128 + ks * 32 + lk * 8);
            af[ks] = pack8(xp4[0], xp4[1]);
        }

        // xp GEMM in two nr-halves (acc[4] caps register pressure)
#pragma unroll
        for (int nh = 0; nh < 2; ++nh) {
            f32x4 acc[4];
#pragma unroll
            for (int nr = 0; nr < 4; ++nr) acc[nr] = z4;
#pragma unroll
            for (int ks = 0; ks < 4; ++ks)
#pragma unroll
                for (int nr = 0; nr < 4; ++nr) {
                    bf16x8 bfrag = *(const bf16x8*)&Wb[((nh * 4 + nr) * 16 + lr) * 64 + ks * 16 + lk * 4];
                    acc[nr] = __builtin_amdgcn_mfma_f32_16x16x32_bf16(af[ks], bfrag, acc[nr], 0, 0, 0);
                }
#pragma unroll
            for (int nr = 0; nr < 4; ++nr)
#pragma unroll
                for (int r = 0; r < 4; ++r) {
                    int row = w * 16 + lk * 4 + r;
                    XPs[row * 136 + (nh * 4 + nr) * 16 + lr] =
                        f2bfu(((const float*)&acc[nr])[r] + binv[nh * 4 + nr]);
                }
        }
        // own XP rows back as A-frags (same-wave write/read)
        bf16x8 xf[4];
#pragma unroll
        for (int ks = 0; ks < 4; ++ks)
            xf[ks] = *(const bf16x8*)&XPs[(w * 16 + lr) * 136 + ks * 32 + lk * 8];
        // score MFMA (B from global Wa, 4KB L1-hot)
        f32x4 sacc = z4;
#pragma unroll
        for (int ks = 0; ks < 4; ++ks) {
            bf16x8 bfrag = *(const bf16x8*)&Wa[lr * 64 + ks * 16 + lk * 4];
            sacc = __builtin_amdgcn_mfma_f32_16x16x32_bf16(xf[ks], bfrag, sacc, 0, 0, 0);
        }
        if (lr < A_HEADS) {
#pragma unroll
            for (int r = 0; r < 4; ++r) {
                int row = w * 16 + lk * 4 + r;
                scoref[row * 8 + lr] = __expf(-fabsf(((const float*)&sacc)[r] + ba));
            }
        }
        // out_part GEMM K=256 (B-frags from global bf16 Wo, L2-hot)
        f32x4 aco[4];
#pragma unroll
        for (int nr = 0; nr < 4; ++nr) aco[nr] = z4;
#pragma unroll
        for (int ks = 0; ks < 4; ++ks)
#pragma unroll
            for (int nr = 0; nr < 4; ++nr) {
                bf16x8 b0 = *(const bf16x8*)&Wo[(nr * 16 + lr) * 128 + ks * 16 + lk * 4];
                aco[nr] = __builtin_amdgcn_mfma_f32_16x16x32_bf16(af[ks], b0, aco[nr], 0, 0, 0);
                bf16x8 b1 = *(const bf16x8*)&Wo[(nr * 16 + lr) * 128 + 64 + ks * 16 + lk * 4];
                aco[nr] = __builtin_amdgcn_mfma_f32_16x16x32_bf16(xf[ks], b1, aco[nr], 0, 0, 0);
            }
#pragma unroll
        for (int nr = 0; nr < 4; ++nr)
#pragma unroll
            for (int r = 0; r < 4; ++r) {
                int n = c0 + w * 16 + lk * 4 + r;
                if (n < s1)
                    opart16[(size_t)n * 64 + nr * 16 + lr] = f2bfu(((const float*)&aco[nr])[r]);
            }
        __syncthreads();   // XP + scoref visible to all waves

        // register agg: thread = (head a0, feat pair 2*f2,2*f2+1)
#pragma unroll 4
        for (int i = 0; i < rc; ++i) {
            unsigned u = XP[i * 68 + f2];
            float sa = scoref[i * 8 + a0];
            float e0 = sa * bfl(u), e1 = sa * bfh(u);
            sum0 += e0; sum1 += e1;
            mx0 = fmaxf(mx0, e0); mx1 = fmaxf(mx1, e1);
        }
        __syncthreads();   // before next chunk overwrites XP/scoref
    }

    // ---- agg vector into XPf ----
    const float inv = 1.f / (float)cnt;
    XPf[a0 * 256 + 2 * f2]           = sum0 * inv;
    XPf[a0 * 256 + 2 * f2 + 1]       = sum1 * inv;
    XPf[a0 * 256 + 128 + 2 * f2]     = mx0;
    XPf[a0 * 256 + 128 + 2 * f2 + 1] = mx1;
    __syncthreads();

    // ---- projection via bf16 Wagg: wave w -> outputs w*8..w*8+7 ----
#pragma unroll
    for (int i = 0; i < 8; ++i) {
        int o = w * 8 + i;
        const unsigned* wrow = Wagg + (size_t)o * 1024;
        float partial = 0.f;
#pragma unroll
        for (int c = 0; c < 4; ++c) {
            int j4 = c * 256 + l * 4;
            uint4 wv = *(const uint4*)&wrow[j4];
            const float* av = &XPf[2 * j4];
            partial = fmaf(bfl(wv.x), av[0], partial);
            partial = fmaf(bfh(wv.x), av[1], partial);
            partial = fmaf(bfl(wv.y), av[2], partial);
            partial = fmaf(bfh(wv.y), av[3], partial);
            partial = fmaf(bfl(wv.z), av[4], partial);
            partial = fmaf(bfh(wv.z), av[5], partial);
            partial = fmaf(bfl(wv.w), av[6], partial);
            partial = fmaf(bfh(wv.w), av[7], partial);
        }
#pragma unroll
        for (int m = 1; m < 64; m <<= 1) partial += __shfl_xor(partial, m);
        if (l == 0) projL[o] = partial + b_out[o];
    }
    __syncthreads();

    // ---- final: out = relu(out_part + projL) for own rows ----
    const int rr = t >> 3, cg = t & 7;
    float p[8];
#pragma unroll
    for (int j = 0; j < 8; ++j) p[j] = projL[cg * 8 + j];
    for (int r0 = s0; r0 < s1; r0 += 64) {
        int row = r0 + rr;
        if (row < s1) {
            uint4 v = *(const uint4*)&out_part_u32[(size_t)row * 32 + cg * 4];
            float4 o0, o1;
            o0.x = fmaxf(bfl(v.x) + p[0], 0.f);
            o0.y = fmaxf(bfh(v.x) + p[1], 0.f);
            o0.z = fmaxf(bfl(v.y) + p[2], 0.f);
            o0.w = fmaxf(bfh(v.y) + p[3], 0.f);
            o1.x = fmaxf(bfl(v.z) + p[4], 0.f);
            o1.y = fmaxf(bfh(v.z) + p[5], 0.f);
            o1.z = fmaxf(bfl(v.w) + p[6], 0.f);
            o1.w = fmaxf(bfh(v.w) + p[7], 0.f);
            *(float4*)&out[(size_t)row * 64 + cg * 8] = o0;
            *(float4*)&out[(size_t)row * 64 + cg * 8 + 4] = o1;
        }
    }
}

extern "C" void kernel_launch(void* const* d_in, const int* in_sizes, int n_in,
                              void* d_out, int out_size, void* d_ws, size_t ws_size,
                              hipStream_t stream) {
    const float* x     = (const float*)d_in[0];
    const int*   batch = (const int*)d_in[1];
    const float* W_in  = (const float*)d_in[3];
    const float* b_in  = (const float*)d_in[4];
    const float* W_a   = (const float*)d_in[5];
    const float* b_a   = (const float*)d_in[6];
    const float* W_out = (const float*)d_in[7];
    const float* b_out = (const float*)d_in[8];
    float* out = (float*)d_out;

    int* seg_start  = (int*)d_ws;                            // 520 ints
    unsigned* Wb    = (unsigned*)(seg_start + 520);          // 8192
    unsigned* Wa    = Wb + 8192;                             // 1024
    unsigned* Wo    = Wa + 1024;                             // 8192
    unsigned* Wagg  = Wo + 8192;                             // 65536
    unsigned* out_part_u32 = Wagg + 65536;                   // N*32 u32

    seg_bounds_kernel<<<1, 1024, 0, stream>>>(batch, N_NODES, seg_start);
    wconv_kernel<<<324, 256, 0, stream>>>(W_in, W_a, W_out, Wb, Wa, Wo, Wagg);
    mega_kernel<<<B_SEGS, 512, 0, stream>>>(
        x, seg_start, b_in, b_a, b_out, Wb, Wa, Wo, Wagg, out_part_u32, out);
}

// Round 11
// 70.919 us; speedup vs baseline: 1.8040x; 1.8040x over previous
//
#include <hip/hip_runtime.h>
#include <math.h>

#define N_NODES 100000
#define D_INPUT 128
#define FDIM 128
#define A_HEADS 8
#define B_SEGS 512
#define D_OUTPUT 64
#define H_DIM 2304

typedef __attribute__((ext_vector_type(8))) __bf16 bf16x8;
typedef __attribute__((ext_vector_type(4))) float f32x4;

static __device__ inline unsigned short f2bfu(float f) {
    unsigned u = __builtin_bit_cast(unsigned, f);
    u += 0x7fffu + ((u >> 16) & 1u);
    return (unsigned short)(u >> 16);
}
static __device__ inline unsigned packbf(float a, float b) {
    return (unsigned)f2bfu(a) | ((unsigned)f2bfu(b) << 16);
}
static __device__ inline float bfl(unsigned u) {
    unsigned x = u << 16; return __builtin_bit_cast(float, x);
}
static __device__ inline float bfh(unsigned u) {
    unsigned x = u & 0xffff0000u; return __builtin_bit_cast(float, x);
}
static __device__ inline bf16x8 pack8(float4 a, float4 b) {
    union { unsigned u[4]; bf16x8 v; } r;
    r.u[0] = packbf(a.x, a.y); r.u[1] = packbf(a.z, a.w);
    r.u[2] = packbf(b.x, b.y); r.u[3] = packbf(b.z, b.w);
    return r.v;
}

// ---------------- segment boundaries (batch is sorted) ----------------
__global__ void seg_bounds_kernel(const int* __restrict__ batch, int n,
                                  int* __restrict__ seg_start) {
    int b = threadIdx.x;
    if (b > B_SEGS) return;
    int lo = 0, hi = n;
    while (lo < hi) {
        int mid = (lo + hi) >> 1;
        if (batch[mid] < b) lo = mid + 1; else hi = mid;
    }
    seg_start[b] = lo;
}

// ------- one-time weight conversion fp32 -> bf16 (packed u32), global -------
__global__ __launch_bounds__(256) void wconv_kernel(
        const float* __restrict__ W_in, const float* __restrict__ W_a,
        const float* __restrict__ W_out, unsigned* __restrict__ Wb,
        unsigned* __restrict__ Wa, unsigned* __restrict__ Wo,
        unsigned* __restrict__ Wagg) {
    int i = blockIdx.x * 256 + threadIdx.x;
    if (i < 8192) {
        float2 v = *(const float2*)(W_in + (size_t)i * 2);
        Wb[i] = packbf(v.x, v.y);
    } else if (i < 9216) {
        int j = i - 8192;
        if (j < 512) {
            float2 v = *(const float2*)(W_a + (size_t)j * 2);
            Wa[j] = packbf(v.x, v.y);
        } else Wa[j] = 0u;
    } else if (i < 17408) {
        int j = i - 9216;
        int row = j >> 7, cu = j & 127;
        float2 v = *(const float2*)(W_out + (size_t)row * H_DIM + cu * 2);
        Wo[j] = packbf(v.x, v.y);
    } else if (i < 82944) {
        int j = i - 17408;
        int row = j >> 10, cu = j & 1023;
        float2 v = *(const float2*)(W_out + (size_t)row * H_DIM + 256 + cu * 2);
        Wagg[j] = packbf(v.x, v.y);
    }
}

// ---- segment-major mega: one block per segment, 512 threads, fully fused ----
// All weights staged in LDS (bf16, uint4 copies from pre-converted global).
// Power-of-2 row strides + XOR swizzle (u32idx ^= (row&7)<<2) on every LDS
// tile: kills the 8-way ds_read_b128 bank conflicts (2.7M measured R8/R9).
// NOTE: min-waves floor of 4 forces VGPR=64 -> accumulator spill (R6/R7/R10:
// symmetric +~100MB FETCH/WRITE scratch traffic). Keep the floor at 2.
__global__ __launch_bounds__(512, 2) void mega_kernel(
        const float* __restrict__ x, const int* __restrict__ seg_start,
        const float* __restrict__ b_in, const float* __restrict__ b_a,
        const float* __restrict__ b_out, const unsigned* __restrict__ Wb,
        const unsigned* __restrict__ Wa, const unsigned* __restrict__ Wo,
        const unsigned* __restrict__ Wagg, unsigned* __restrict__ out_part_u32,
        float* __restrict__ out) {
    __shared__ __align__(16) unsigned WbL[128 * 64];   // W_in bf16 (swizzled)
    __shared__ __align__(16) unsigned WaL[16 * 64];    // W_a bf16 (swizzled)
    __shared__ __align__(16) unsigned WoL[64 * 128];   // W_out[:,:256] (swizzled)
    __shared__ __align__(16) unsigned XP[128 * 64];    // xp chunk bf16 / agg f32
    __shared__ float scoref[128 * 8];
    __shared__ float projL[64];
    unsigned short* XPs = (unsigned short*)XP;
    float* XPf = (float*)XP;
    unsigned short* opart16 = (unsigned short*)out_part_u32;

    const int b = blockIdx.x;
    const int s0 = seg_start[b], s1 = seg_start[b + 1];
    const int cnt = s1 - s0;
    if (cnt == 0) return;
    const int t = threadIdx.x;

    // ---- stage weights: pure uint4 copies, swizzled on 16B units ----
    {
        const uint4* srcb = (const uint4*)Wb;      // 2048 uint4, rows of 16
#pragma unroll
        for (int i = 0; i < 4; ++i) {
            int idx = i * 512 + t;
            int row = idx >> 4, c4 = idx & 15;
            *(uint4*)&WbL[row * 64 + ((c4 * 4) ^ ((row & 7) << 2))] = srcb[idx];
        }
        const uint4* srco = (const uint4*)Wo;      // 2048 uint4, rows of 32
#pragma unroll
        for (int i = 0; i < 4; ++i) {
            int idx = i * 512 + t;
            int row = idx >> 5, c4 = idx & 31;
            *(uint4*)&WoL[row * 128 + ((c4 * 4) ^ ((row & 7) << 2))] = srco[idx];
        }
        if (t < 256) {                             // Wa: 256 uint4, rows of 16
            const uint4* sa = (const uint4*)Wa;
            int row = t >> 4, c4 = t & 15;
            *(uint4*)&WaL[row * 64 + ((c4 * 4) ^ ((row & 7) << 2))] = sa[t];
        }
    }
    __syncthreads();

    const int w = t >> 6, l = t & 63, lr = l & 15, lk = l >> 4;
    const int a0 = w, f2 = l;       // agg ownership: head w, feat pair 2l,2l+1
    const int swz = (lr & 7) << 2;  // u32-unit swizzle for weight-row reads
    const int swzh = (lr & 7) << 3; // u16-unit swizzle for xf reads

    float binv[8];
#pragma unroll
    for (int nr = 0; nr < 8; ++nr) binv[nr] = b_in[nr * 16 + lr];
    const float ba = b_a[lr & 7];

    const f32x4 z4 = {0.f, 0.f, 0.f, 0.f};
    float sum0 = 0.f, sum1 = 0.f, mx0 = -INFINITY, mx1 = -INFINITY;

    for (int c0 = s0; c0 < s1; c0 += 128) {
        const int rc = min(128, s1 - c0);
        const int arowc = min(c0 + w * 16 + lr, s1 - 1);

        bf16x8 af[4];
#pragma unroll
        for (int ks = 0; ks < 4; ++ks) {
            const float4* xp4 = (const float4*)(x + (size_t)arowc * 128 + ks * 32 + lk * 8);
            af[ks] = pack8(xp4[0], xp4[1]);
        }

        // xp GEMM in two nr-halves (acc[4] caps register pressure)
#pragma unroll
        for (int nh = 0; nh < 2; ++nh) {
            f32x4 acc[4];
#pragma unroll
            for (int nr = 0; nr < 4; ++nr) acc[nr] = z4;
#pragma unroll
            for (int ks = 0; ks < 4; ++ks)
#pragma unroll
                for (int nr = 0; nr < 4; ++nr) {
                    bf16x8 bfrag = *(const bf16x8*)&WbL[((nh * 4 + nr) * 16 + lr) * 64
                                                        + ((ks * 16 + lk * 4) ^ swz)];
                    acc[nr] = __builtin_amdgcn_mfma_f32_16x16x32_bf16(af[ks], bfrag, acc[nr], 0, 0, 0);
                }
#pragma unroll
            for (int nr = 0; nr < 4; ++nr)
#pragma unroll
                for (int r = 0; r < 4; ++r) {
                    int row = w * 16 + lk * 4 + r;
                    XPs[row * 128 + (((nh * 4 + nr) * 16 + lr) ^ ((row & 7) << 3))] =
                        f2bfu(((const float*)&acc[nr])[r] + binv[nh * 4 + nr]);
                }
        }
        // own XP rows back as A-frags (same-wave write/read, swizzled)
        bf16x8 xf[4];
        {
            const int xrow = w * 16 + lr;
#pragma unroll
            for (int ks = 0; ks < 4; ++ks)
                xf[ks] = *(const bf16x8*)&XPs[xrow * 128 + ((ks * 32 + lk * 8) ^ swzh)];
        }
        // score MFMA
        f32x4 sacc = z4;
#pragma unroll
        for (int ks = 0; ks < 4; ++ks) {
            bf16x8 bfrag = *(const bf16x8*)&WaL[lr * 64 + ((ks * 16 + lk * 4) ^ swz)];
            sacc = __builtin_amdgcn_mfma_f32_16x16x32_bf16(xf[ks], bfrag, sacc, 0, 0, 0);
        }
        if (lr < A_HEADS) {
#pragma unroll
            for (int r = 0; r < 4; ++r) {
                int row = w * 16 + lk * 4 + r;
                scoref[row * 8 + lr] = __expf(-fabsf(((const float*)&sacc)[r] + ba));
            }
        }
        // out_part GEMM K=256 (B-frags from LDS WoL, swizzled)
        f32x4 aco[4];
#pragma unroll
        for (int nr = 0; nr < 4; ++nr) aco[nr] = z4;
#pragma unroll
        for (int ks = 0; ks < 4; ++ks)
#pragma unroll
            for (int nr = 0; nr < 4; ++nr) {
                bf16x8 b0 = *(const bf16x8*)&WoL[(nr * 16 + lr) * 128
                                                 + ((ks * 16 + lk * 4) ^ swz)];
                aco[nr] = __builtin_amdgcn_mfma_f32_16x16x32_bf16(af[ks], b0, aco[nr], 0, 0, 0);
                bf16x8 b1 = *(const bf16x8*)&WoL[(nr * 16 + lr) * 128
                                                 + ((64 + ks * 16 + lk * 4) ^ swz)];
                aco[nr] = __builtin_amdgcn_mfma_f32_16x16x32_bf16(xf[ks], b1, aco[nr], 0, 0, 0);
            }
#pragma unroll
        for (int nr = 0; nr < 4; ++nr)
#pragma unroll
            for (int r = 0; r < 4; ++r) {
                int n = c0 + w * 16 + lk * 4 + r;
                if (n < s1)
                    opart16[(size_t)n * 64 + nr * 16 + lr] = f2bfu(((const float*)&aco[nr])[r]);
            }
        __syncthreads();   // XP + scoref visible to all waves

        // register agg: thread = (head a0, feat pair 2*f2,2*f2+1), swizzled read
#pragma unroll 4
        for (int i = 0; i < rc; ++i) {
            unsigned u = XP[i * 64 + (f2 ^ ((i & 7) << 2))];
            float sa = scoref[i * 8 + a0];
            float e0 = sa * bfl(u), e1 = sa * bfh(u);
            sum0 += e0; sum1 += e1;
            mx0 = fmaxf(mx0, e0); mx1 = fmaxf(mx1, e1);
        }
        __syncthreads();   // before next chunk overwrites XP/scoref
    }

    // ---- agg vector into XPf (plain layout; different phase) ----
    const float inv = 1.f / (float)cnt;
    XPf[a0 * 256 + 2 * f2]           = sum0 * inv;
    XPf[a0 * 256 + 2 * f2 + 1]       = sum1 * inv;
    XPf[a0 * 256 + 128 + 2 * f2]     = mx0;
    XPf[a0 * 256 + 128 + 2 * f2 + 1] = mx1;
    __syncthreads();

    // ---- projection via bf16 Wagg (global, L2-hot): wave w -> outs w*8.. ----
#pragma unroll
    for (int i = 0; i < 8; ++i) {
        int o = w * 8 + i;
        const unsigned* wrow = Wagg + (size_t)o * 1024;
        float partial = 0.f;
#pragma unroll
        for (int c = 0; c < 4; ++c) {
            int j4 = c * 256 + l * 4;
            uint4 wv = *(const uint4*)&wrow[j4];
            const float* av = &XPf[2 * j4];
            partial = fmaf(bfl(wv.x), av[0], partial);
            partial = fmaf(bfh(wv.x), av[1], partial);
            partial = fmaf(bfl(wv.y), av[2], partial);
            partial = fmaf(bfh(wv.y), av[3], partial);
            partial = fmaf(bfl(wv.z), av[4], partial);
            partial = fmaf(bfh(wv.z), av[5], partial);
            partial = fmaf(bfl(wv.w), av[6], partial);
            partial = fmaf(bfh(wv.w), av[7], partial);
        }
#pragma unroll
        for (int m = 1; m < 64; m <<= 1) partial += __shfl_xor(partial, m);
        if (l == 0) projL[o] = partial + b_out[o];
    }
    __syncthreads();

    // ---- final: out = relu(out_part + projL) for own rows ----
    const int rr = t >> 3, cg = t & 7;
    float p[8];
#pragma unroll
    for (int j = 0; j < 8; ++j) p[j] = projL[cg * 8 + j];
    for (int r0 = s0; r0 < s1; r0 += 64) {
        int row = r0 + rr;
        if (row < s1) {
            uint4 v = *(const uint4*)&out_part_u32[(size_t)row * 32 + cg * 4];
            float4 o0, o1;
            o0.x = fmaxf(bfl(v.x) + p[0], 0.f);
            o0.y = fmaxf(bfh(v.x) + p[1], 0.f);
            o0.z = fmaxf(bfl(v.y) + p[2], 0.f);
            o0.w = fmaxf(bfh(v.y) + p[3], 0.f);
            o1.x = fmaxf(bfl(v.z) + p[4], 0.f);
            o1.y = fmaxf(bfh(v.z) + p[5], 0.f);
            o1.z = fmaxf(bfl(v.w) + p[6], 0.f);
            o1.w = fmaxf(bfh(v.w) + p[7], 0.f);
            *(float4*)&out[(size_t)row * 64 + cg * 8] = o0;
            *(float4*)&out[(size_t)row * 64 + cg * 8 + 4] = o1;
        }
    }
}

extern "C" void kernel_launch(void* const* d_in, const int* in_sizes, int n_in,
                              void* d_out, int out_size, void* d_ws, size_t ws_size,
                              hipStream_t stream) {
    const float* x     = (const float*)d_in[0];
    const int*   batch = (const int*)d_in[1];
    const float* W_in  = (const float*)d_in[3];
    const float* b_in  = (const float*)d_in[4];
    const float* W_a   = (const float*)d_in[5];
    const float* b_a   = (const float*)d_in[6];
    const float* W_out = (const float*)d_in[7];
    const float* b_out = (const float*)d_in[8];
    float* out = (float*)d_out;

    int* seg_start  = (int*)d_ws;                            // 520 ints
    unsigned* Wb    = (unsigned*)(seg_start + 520);          // 8192
    unsigned* Wa    = Wb + 8192;                             // 1024
    unsigned* Wo    = Wa + 1024;                             // 8192
    unsigned* Wagg  = Wo + 8192;                             // 65536
    unsigned* out_part_u32 = Wagg + 65536;                   // N*32 u32

    seg_bounds_kernel<<<1, 1024, 0, stream>>>(batch, N_NODES, seg_start);
    wconv_kernel<<<324, 256, 0, stream>>>(W_in, W_a, W_out, Wb, Wa, Wo, Wagg);
    mega_kernel<<<B_SEGS, 512, 0, stream>>>(
        x, seg_start, b_in, b_a, b_out, Wb, Wa, Wo, Wagg, out_part_u32, out);
}